// Round 1
// baseline (1274.075 us; speedup 1.0000x reference)
//
#include <hip/hip_runtime.h>
#include <stdint.h>

// Problem constants (from reference): B=2, L=2048, E=1024, H=16, Dk=Dv=64, top_k=32, T=0.7
constexpr int L = 2048;
constexpr int H = 16;
constexpr float SCALE = 0.17857142857142858f;   // 1/(sqrt(64)*0.7)
constexpr int OUT0 = 2 * 2048 * 64;             // output region floats; probs follow

__device__ __forceinline__ float wave_fmax(float x) {
#pragma unroll
  for (int s = 32; s; s >>= 1) x = fmaxf(x, __shfl_xor(x, s));
  return x;
}
__device__ __forceinline__ float wave_fsum(float x) {
#pragma unroll
  for (int s = 32; s; s >>= 1) x += __shfl_xor(x, s);
  return x;
}
__device__ __forceinline__ int wave_isum(int x) {
#pragma unroll
  for (int s = 32; s; s >>= 1) x += __shfl_xor(x, s);
  return x;
}
__device__ __forceinline__ unsigned f2sort(float f) {
  unsigned u = __float_as_uint(f);
  return (u & 0x80000000u) ? ~u : (u | 0x80000000u);
}

// ---------------- Projection GEMM: Y[b][h][l][d] = sum_e X[b*L+l][e] * W[h*64+d][e]
// M=4096 tokens, N=1024 outs, K template (1024 for q/k, 64 for v). 64x64 tile, 4x4/thread.
template <int K>
__global__ __launch_bounds__(256) void proj_kernel(const float* __restrict__ X,
                                                   const float* __restrict__ W,
                                                   float* __restrict__ Y) {
  __shared__ float As[16][64];
  __shared__ float Bs[16][64];
  const int t = threadIdx.x;
  const int tx = t & 15, ty = t >> 4;
  const int m0 = blockIdx.y * 64;
  const int n0 = blockIdx.x * 64;
  const int lm = t >> 2;
  const int lk = (t & 3) * 4;
  const float* xg = X + (size_t)(m0 + lm) * K + lk;
  const float* wg = W + (size_t)(n0 + lm) * K + lk;
  float acc[4][4] = {};
  for (int k0 = 0; k0 < K; k0 += 16) {
    float4 a4 = *(const float4*)(xg + k0);
    float4 b4 = *(const float4*)(wg + k0);
    __syncthreads();
    As[lk + 0][lm] = a4.x; As[lk + 1][lm] = a4.y; As[lk + 2][lm] = a4.z; As[lk + 3][lm] = a4.w;
    Bs[lk + 0][lm] = b4.x; Bs[lk + 1][lm] = b4.y; Bs[lk + 2][lm] = b4.z; Bs[lk + 3][lm] = b4.w;
    __syncthreads();
#pragma unroll
    for (int kk = 0; kk < 16; ++kk) {
      float4 av = *(const float4*)&As[kk][ty * 4];
      float4 bv = *(const float4*)&Bs[kk][tx * 4];
      float ar[4] = {av.x, av.y, av.z, av.w};
      float br[4] = {bv.x, bv.y, bv.z, bv.w};
#pragma unroll
      for (int i = 0; i < 4; ++i)
#pragma unroll
        for (int j = 0; j < 4; ++j) acc[i][j] = fmaf(ar[i], br[j], acc[i][j]);
    }
  }
  const int n = n0 + tx * 4;
  const int h = n >> 6, d = n & 63;
#pragma unroll
  for (int i = 0; i < 4; ++i) {
    int mm = m0 + ty * 4 + i;
    int b = mm >> 11, l = mm & 2047;
    *(float4*)&Y[(((size_t)b * H + h) * L + l) * 64 + d] =
        make_float4(acc[i][0], acc[i][1], acc[i][2], acc[i][3]);
  }
}

// ---------------- Logits batched GEMM: Lg[bh][i][j] = SCALE * dot64(Qp[bh][i], Kp[bh][j])
__global__ __launch_bounds__(256) void logits_kernel(const float* __restrict__ Qp,
                                                     const float* __restrict__ Kp,
                                                     float* __restrict__ Lg) {
  __shared__ float As[16][64];
  __shared__ float Bs[16][64];
  const int t = threadIdx.x;
  const int tx = t & 15, ty = t >> 4;
  const int bh = blockIdx.z;
  const int m0 = blockIdx.y * 64;
  const int n0 = blockIdx.x * 64;
  const int lm = t >> 2;
  const int lk = (t & 3) * 4;
  const float* A = Qp + (size_t)bh * L * 64 + (size_t)(m0 + lm) * 64 + lk;
  const float* B = Kp + (size_t)bh * L * 64 + (size_t)(n0 + lm) * 64 + lk;
  float acc[4][4] = {};
  for (int k0 = 0; k0 < 64; k0 += 16) {
    float4 a4 = *(const float4*)(A + k0);
    float4 b4 = *(const float4*)(B + k0);
    __syncthreads();
    As[lk + 0][lm] = a4.x; As[lk + 1][lm] = a4.y; As[lk + 2][lm] = a4.z; As[lk + 3][lm] = a4.w;
    Bs[lk + 0][lm] = b4.x; Bs[lk + 1][lm] = b4.y; Bs[lk + 2][lm] = b4.z; Bs[lk + 3][lm] = b4.w;
    __syncthreads();
#pragma unroll
    for (int kk = 0; kk < 16; ++kk) {
      float4 av = *(const float4*)&As[kk][ty * 4];
      float4 bv = *(const float4*)&Bs[kk][tx * 4];
      float ar[4] = {av.x, av.y, av.z, av.w};
      float br[4] = {bv.x, bv.y, bv.z, bv.w};
#pragma unroll
      for (int i = 0; i < 4; ++i)
#pragma unroll
        for (int j = 0; j < 4; ++j) acc[i][j] = fmaf(ar[i], br[j], acc[i][j]);
    }
  }
  float* C = Lg + (size_t)bh * L * L;
#pragma unroll
  for (int i = 0; i < 4; ++i) {
    int mm = m0 + ty * 4 + i;
    *(float4*)&C[(size_t)mm * L + n0 + tx * 4] =
        make_float4(acc[i][0] * SCALE, acc[i][1] * SCALE, acc[i][2] * SCALE, acc[i][3] * SCALE);
  }
}

// ---------------- Exact top-32 select + softmax (in-place probs) + sparse PV
// One wave per row; lane holds 32 contiguous logits (global idx = lane*32 + j).
__global__ __launch_bounds__(256) void select_kernel(float* __restrict__ Lg,
                                                     const float* __restrict__ Vp,
                                                     float* __restrict__ Mixed) {
  const int lane = threadIdx.x & 63;
  const int row = blockIdx.x * 4 + (threadIdx.x >> 6);
  const int bh = row >> 11;
  const int q = row & 2047;
  float* Lrow = Lg + (size_t)row * 2048;

  float lg[32];
  {
    const float4* p4 = (const float4*)(Lrow + lane * 32);
#pragma unroll
    for (int u = 0; u < 8; ++u) {
      float4 v4 = p4[u];
      lg[u * 4 + 0] = v4.x; lg[u * 4 + 1] = v4.y; lg[u * 4 + 2] = v4.z; lg[u * 4 + 3] = v4.w;
    }
  }
  float m = lg[0];
#pragma unroll
  for (int j = 1; j < 32; ++j) m = fmaxf(m, lg[j]);
  m = wave_fmax(m);

  // T = bit-exact 32nd-largest value of the row.
  float T = 0.f;
  bool found = false;
  float cut = m - 1.75f;
  float lo = 0.f, hi = m;
  bool has_lo = false;
  for (int attempt = 0; attempt < 8 && !found; ++attempt) {
    int c = 0;
#pragma unroll
    for (int j = 0; j < 32; ++j) c += (lg[j] > cut) ? 1 : 0;
    c = wave_isum(c);
    if (c < 32) {                       // cut too high
      hi = cut;
      cut = has_lo ? 0.5f * (lo + cut) : (m - 3.0f * (m - cut));
    } else if (c > 64) {                // cut too low (exceeds sort capacity)
      lo = cut; has_lo = true;
      cut = 0.5f * (cut + hi);
    } else {
      // gather c candidates (> cut) into one value per lane, pad -inf
      float v = -3.4e38f;
      int cnt = 0;
#pragma unroll
      for (int j = 0; j < 32; ++j) {
        unsigned long long b = __ballot(lg[j] > cut);
        while (b) {
          int s = __builtin_ctzll(b);
          float val = __shfl(lg[j], s);
          if (lane == cnt) v = val;
          ++cnt;
          b &= b - 1;
        }
      }
      // 64-lane bitonic ascending sort
#pragma unroll
      for (int size = 2; size <= 64; size <<= 1) {
#pragma unroll
        for (int stride = size >> 1; stride; stride >>= 1) {
          float pv = __shfl_xor(v, stride);
          bool lower = (lane & stride) == 0;
          bool asc = (lane & size) == 0;
          v = (lower == asc) ? fminf(v, pv) : fmaxf(v, pv);
        }
      }
      T = __shfl(v, 32);                // 32nd largest (largest at lane 63)
      found = true;
    }
  }
  if (!found) {                          // exact radix bisect fallback (degenerate rows)
    unsigned tb = 0;
    for (int bit = 31; bit >= 0; --bit) {
      unsigned cand = tb | (1u << bit);
      int c = 0;
#pragma unroll
      for (int j = 0; j < 32; ++j) c += (f2sort(lg[j]) >= cand) ? 1 : 0;
      c = wave_isum(c);
      if (c >= 32) tb = cand;
    }
    T = (tb & 0x80000000u) ? __uint_as_float(tb & 0x7fffffffu) : __uint_as_float(~tb);
  }

  // Keep mask: all > T, plus ties == T at lowest global index (lax.top_k semantics)
  int cgt = 0, ceq = 0;
#pragma unroll
  for (int j = 0; j < 32; ++j) {
    cgt += (lg[j] > T) ? 1 : 0;
    ceq += (lg[j] == T) ? 1 : 0;
  }
  int total_gt = wave_isum(cgt);
  int need_eq = 32 - total_gt;
  int pre = ceq;                         // exclusive prefix over lanes (lane-major index order)
#pragma unroll
  for (int s = 1; s < 64; s <<= 1) {
    int t2 = __shfl_up(pre, s);
    if (lane >= s) pre += t2;
  }
  pre -= ceq;
  unsigned keepm = 0;
  int r = pre;
#pragma unroll
  for (int j = 0; j < 32; ++j) {
    bool eq = (lg[j] == T);
    bool kp = (lg[j] > T) || (eq && r < need_eq);
    if (eq) ++r;
    keepm |= kp ? (1u << j) : 0u;
  }

  // Softmax over kept; non-kept are exactly 0 (matches exp(f32min - max) == 0)
  float sum = 0.f;
#pragma unroll
  for (int j = 0; j < 32; ++j) {
    float e = ((keepm >> j) & 1u) ? __expf(lg[j] - m) : 0.f;
    lg[j] = e;
    sum += e;
  }
  sum = wave_fsum(sum);
  float inv = 1.0f / sum;
#pragma unroll
  for (int j = 0; j < 32; ++j) lg[j] *= inv;

  {
    float4* p4 = (float4*)(Lrow + lane * 32);
#pragma unroll
    for (int u = 0; u < 8; ++u)
      p4[u] = make_float4(lg[u * 4 + 0], lg[u * 4 + 1], lg[u * 4 + 2], lg[u * 4 + 3]);
  }

  // Gather the 32 kept (prob, key-index) pairs across the wave
  float pk = 0.f;
  int ik = 0;
  int cnt = 0;
#pragma unroll
  for (int j = 0; j < 32; ++j) {
    unsigned long long b = __ballot((keepm >> j) & 1u);
    while (b) {
      int s = __builtin_ctzll(b);
      float pv = __shfl(lg[j], s);
      if (lane == cnt) { pk = pv; ik = s * 32 + j; }
      ++cnt;
      b &= b - 1;
    }
  }

  // Sparse PV: mixed[d=lane] = sum_i p_i * v_proj[bh][idx_i][lane]
  const float* Vb = Vp + (size_t)bh * L * 64;
  float acc = 0.f;
#pragma unroll
  for (int i = 0; i < 32; ++i) {
    float p = __shfl(pk, i);
    int kidx = __shfl(ik, i);
    acc = fmaf(p, Vb[(size_t)kidx * 64 + lane], acc);
  }
  const int bb = bh >> 4, hh = bh & 15;
  Mixed[((size_t)(bb * 2048 + q)) * 1024 + hh * 64 + lane] = acc;
}

// ---------------- Output FC: Out[m][n] = sum_k Mixed[m][k] * Wfc[n][k]  (M=4096,N=64,K=1024)
__global__ __launch_bounds__(256) void fc_kernel(const float* __restrict__ Mx,
                                                 const float* __restrict__ Wfc,
                                                 float* __restrict__ Out) {
  __shared__ float As[32][64];
  __shared__ float Ws[64][64];
  const int t = threadIdx.x;
  const int tx = t & 15;
  const int ty = t >> 4;
  const int m0 = blockIdx.x * 32;
  float acc[2][4] = {};
  for (int k0 = 0; k0 < 1024; k0 += 64) {
    __syncthreads();
    {
      int lin = t * 8;
      int rr = lin >> 6, kk = lin & 63;
      *(float4*)&As[rr][kk] = *(const float4*)&Mx[(size_t)(m0 + rr) * 1024 + k0 + kk];
      *(float4*)&As[rr][kk + 4] = *(const float4*)&Mx[(size_t)(m0 + rr) * 1024 + k0 + kk + 4];
    }
    {
      int n = t >> 2;
      int kq = (t & 3) * 16;
#pragma unroll
      for (int u = 0; u < 4; ++u) {
        float4 wv = *(const float4*)&Wfc[(size_t)n * 1024 + k0 + kq + u * 4];
        Ws[kq + u * 4 + 0][n] = wv.x;
        Ws[kq + u * 4 + 1][n] = wv.y;
        Ws[kq + u * 4 + 2][n] = wv.z;
        Ws[kq + u * 4 + 3][n] = wv.w;
      }
    }
    __syncthreads();
#pragma unroll
    for (int kk = 0; kk < 64; ++kk) {
      float a0 = As[ty][kk], a1 = As[ty + 16][kk];
      float4 wv = *(const float4*)&Ws[kk][tx * 4];
      float wr[4] = {wv.x, wv.y, wv.z, wv.w};
#pragma unroll
      for (int j = 0; j < 4; ++j) {
        acc[0][j] = fmaf(a0, wr[j], acc[0][j]);
        acc[1][j] = fmaf(a1, wr[j], acc[1][j]);
      }
    }
  }
#pragma unroll
  for (int i = 0; i < 2; ++i) {
    int mm = m0 + ty + i * 16;
    *(float4*)&Out[(size_t)mm * 64 + tx * 4] =
        make_float4(acc[i][0], acc[i][1], acc[i][2], acc[i][3]);
  }
}

extern "C" void kernel_launch(void* const* d_in, const int* in_sizes, int n_in,
                              void* d_out, int out_size, void* d_ws, size_t ws_size,
                              hipStream_t stream) {
  const float* q    = (const float*)d_in[0];
  const float* k    = (const float*)d_in[1];
  const float* v    = (const float*)d_in[2];
  const float* w_q  = (const float*)d_in[3];
  const float* w_k  = (const float*)d_in[4];
  const float* w_v  = (const float*)d_in[5];
  const float* w_fc = (const float*)d_in[6];

  float* out = (float*)d_out;
  float* probs = out + OUT0;             // 512 MB probs region doubles as logits scratch

  float* ws = (float*)d_ws;              // 64 MB used: 4 x 16MB
  float* q_proj = ws;                    // [B][H][L][64]
  float* k_proj = ws + 4194304;
  float* v_proj = ws + 2 * 4194304;
  float* mixed  = ws + 3 * 4194304;      // [B*L][1024]

  dim3 blk(256);
  proj_kernel<1024><<<dim3(16, 64), blk, 0, stream>>>(q, w_q, q_proj);
  proj_kernel<1024><<<dim3(16, 64), blk, 0, stream>>>(k, w_k, k_proj);
  proj_kernel<64><<<dim3(16, 64), blk, 0, stream>>>(v, w_v, v_proj);
  logits_kernel<<<dim3(32, 32, 32), blk, 0, stream>>>(q_proj, k_proj, probs);
  select_kernel<<<dim3(16384), blk, 0, stream>>>(probs, v_proj, mixed);
  fc_kernel<<<dim3(128), blk, 0, stream>>>(mixed, w_fc, out);
}

// Round 3
// 1172.824 us; speedup vs baseline: 1.0863x; 1.0863x over previous
//
#include <hip/hip_runtime.h>
#include <stdint.h>
#include <float.h>

// B=2, L=2048, E=1024, H=16, Dk=Dv=64, top_k=32, temperature=0.7
constexpr int L = 2048;
constexpr int H = 16;
constexpr float SCALE = 0.17857142857142858f;   // 1/(sqrt(64)*0.7), folded into q_proj
constexpr int OUT0 = 2 * 2048 * 64;             // output floats; probs follow in d_out

typedef float f32x4 __attribute__((ext_vector_type(4)));  // clang-native for NT stores

__device__ __forceinline__ float wave_fmax(float x) {
#pragma unroll
  for (int s = 32; s; s >>= 1) x = fmaxf(x, __shfl_xor(x, s));
  return x;
}
__device__ __forceinline__ float wave_fsum(float x) {
#pragma unroll
  for (int s = 32; s; s >>= 1) x += __shfl_xor(x, s);
  return x;
}
__device__ __forceinline__ int wave_isum(int x) {
#pragma unroll
  for (int s = 32; s; s >>= 1) x += __shfl_xor(x, s);
  return x;
}
__device__ __forceinline__ unsigned f2sort(float f) {
  unsigned u = __float_as_uint(f);
  return (u & 0x80000000u) ? ~u : (u | 0x80000000u);
}
__device__ __forceinline__ void lds_fence() {
  __asm__ __volatile__("s_waitcnt lgkmcnt(0)" ::: "memory");
}

// ---------------- Projection GEMM: Y[b][h][l][d] = scale * sum_e X[m][e] * W[h*64+d][e]
// M=4096, N=1024, K template. Tile 128(m) x 64(n), 256 thr, micro 8x4.
template <int K>
__global__ __launch_bounds__(256) void proj_kernel(const float* __restrict__ X,
                                                   const float* __restrict__ W,
                                                   float* __restrict__ Y, float scale) {
  __shared__ float As[16][128];
  __shared__ float Bs[16][64];
  const int t = threadIdx.x;
  const int tx = t & 15;        // n quad
  const int ty = t >> 4;        // m octet
  const int m0 = blockIdx.y * 128;
  const int n0 = blockIdx.x * 64;
  const int ar = t >> 1, ac = (t & 1) * 8;
  const int br = t >> 2, bc = (t & 3) * 4;
  const float* xg = X + (size_t)(m0 + ar) * K + ac;
  const float* wg = W + (size_t)(n0 + br) * K + bc;
  float acc[8][4] = {};
  for (int k0 = 0; k0 < K; k0 += 16) {
    float4 a0 = *(const float4*)(xg + k0);
    float4 a1 = *(const float4*)(xg + k0 + 4);
    float4 b0 = *(const float4*)(wg + k0);
    __syncthreads();
    As[ac + 0][ar] = a0.x; As[ac + 1][ar] = a0.y; As[ac + 2][ar] = a0.z; As[ac + 3][ar] = a0.w;
    As[ac + 4][ar] = a1.x; As[ac + 5][ar] = a1.y; As[ac + 6][ar] = a1.z; As[ac + 7][ar] = a1.w;
    Bs[bc + 0][br] = b0.x; Bs[bc + 1][br] = b0.y; Bs[bc + 2][br] = b0.z; Bs[bc + 3][br] = b0.w;
    __syncthreads();
#pragma unroll
    for (int kk = 0; kk < 16; ++kk) {
      float4 av0 = *(const float4*)&As[kk][ty * 8];
      float4 av1 = *(const float4*)&As[kk][ty * 8 + 4];
      float4 bv = *(const float4*)&Bs[kk][tx * 4];
      float ar8[8] = {av0.x, av0.y, av0.z, av0.w, av1.x, av1.y, av1.z, av1.w};
      float br4[4] = {bv.x, bv.y, bv.z, bv.w};
#pragma unroll
      for (int i = 0; i < 8; ++i)
#pragma unroll
        for (int j = 0; j < 4; ++j) acc[i][j] = fmaf(ar8[i], br4[j], acc[i][j]);
    }
  }
  const int n = n0 + tx * 4;
  const int h = n >> 6, d = n & 63;
#pragma unroll
  for (int i = 0; i < 8; ++i) {
    int mm = m0 + ty * 8 + i;
    int b = mm >> 11, l = mm & 2047;
    *(float4*)&Y[(((size_t)b * H + h) * L + l) * 64 + d] =
        make_float4(acc[i][0] * scale, acc[i][1] * scale, acc[i][2] * scale, acc[i][3] * scale);
  }
}

// ---------------- Logits batched GEMM: Lg[bh][i][j] = dot64(Qp[bh][i], Kp[bh][j])
// Tile 128(q) x 64(k), micro 8x4, K=64. Nontemporal C store (512 MB stream).
__global__ __launch_bounds__(256) void logits_kernel(const float* __restrict__ Qp,
                                                     const float* __restrict__ Kp,
                                                     float* __restrict__ Lg) {
  __shared__ float As[16][128];
  __shared__ float Bs[16][64];
  const int t = threadIdx.x;
  const int tx = t & 15, ty = t >> 4;
  const int bh = blockIdx.z;
  const int m0 = blockIdx.y * 128;
  const int n0 = blockIdx.x * 64;
  const int ar = t >> 1, ac = (t & 1) * 8;
  const int br = t >> 2, bc = (t & 3) * 4;
  const float* A = Qp + (size_t)bh * L * 64 + (size_t)(m0 + ar) * 64 + ac;
  const float* Bp = Kp + (size_t)bh * L * 64 + (size_t)(n0 + br) * 64 + bc;
  float acc[8][4] = {};
#pragma unroll 1
  for (int k0 = 0; k0 < 64; k0 += 16) {
    float4 a0 = *(const float4*)(A + k0);
    float4 a1 = *(const float4*)(A + k0 + 4);
    float4 b0 = *(const float4*)(Bp + k0);
    __syncthreads();
    As[ac + 0][ar] = a0.x; As[ac + 1][ar] = a0.y; As[ac + 2][ar] = a0.z; As[ac + 3][ar] = a0.w;
    As[ac + 4][ar] = a1.x; As[ac + 5][ar] = a1.y; As[ac + 6][ar] = a1.z; As[ac + 7][ar] = a1.w;
    Bs[bc + 0][br] = b0.x; Bs[bc + 1][br] = b0.y; Bs[bc + 2][br] = b0.z; Bs[bc + 3][br] = b0.w;
    __syncthreads();
#pragma unroll
    for (int kk = 0; kk < 16; ++kk) {
      float4 av0 = *(const float4*)&As[kk][ty * 8];
      float4 av1 = *(const float4*)&As[kk][ty * 8 + 4];
      float4 bv = *(const float4*)&Bs[kk][tx * 4];
      float ar8[8] = {av0.x, av0.y, av0.z, av0.w, av1.x, av1.y, av1.z, av1.w};
      float br4[4] = {bv.x, bv.y, bv.z, bv.w};
#pragma unroll
      for (int i = 0; i < 8; ++i)
#pragma unroll
        for (int j = 0; j < 4; ++j) acc[i][j] = fmaf(ar8[i], br4[j], acc[i][j]);
    }
  }
  float* C = Lg + (size_t)bh * L * L;
#pragma unroll
  for (int i = 0; i < 8; ++i) {
    int mm = m0 + ty * 8 + i;
    f32x4 cv = {acc[i][0], acc[i][1], acc[i][2], acc[i][3]};
    __builtin_nontemporal_store(cv, (f32x4*)&C[(size_t)mm * L + n0 + tx * 4]);
  }
}

// ---------------- Exact top-32 select + softmax (in-place probs) + sparse PV
// One wave per row. Strided layout: lane holds keys j = u*64 + lane, u=0..31.
__global__ __launch_bounds__(256) void select_kernel(float* __restrict__ Lg,
                                                     const float* __restrict__ Vp,
                                                     float* __restrict__ Mixed) {
  __shared__ float cbuf[4][64];
  __shared__ float pbuf[4][32];
  __shared__ int ibuf[4][32];
  const int lane = threadIdx.x & 63;
  const int w = threadIdx.x >> 6;
  const int row = blockIdx.x * 4 + w;
  const int bh = row >> 11;
  const int q = row & 2047;
  float* Lrow = Lg + (size_t)row * 2048;
  const unsigned long long below = (lane == 63) ? 0x7fffffffffffffffull
                                                : ((1ull << lane) - 1ull);

  float lg[32];
#pragma unroll
  for (int u = 0; u < 32; ++u)
    lg[u] = __builtin_nontemporal_load(Lrow + u * 64 + lane);

  float m = lg[0];
#pragma unroll
  for (int u = 1; u < 32; ++u) m = fmaxf(m, lg[u]);
  m = wave_fmax(m);

  // ---- T = bit-exact 32nd-largest row value
  float T = 0.f;
  bool found = false;
  float cut = m - 2.2f;
  float lo = 0.f, hi = m;
  bool has_lo = false;
  for (int attempt = 0; attempt < 8 && !found; ++attempt) {
    int c = 0;
#pragma unroll
    for (int u = 0; u < 32; ++u) c += (lg[u] > cut) ? 1 : 0;
    c = wave_isum(c);
    if (c < 32) {
      hi = cut;
      cut = has_lo ? 0.5f * (lo + cut) : (cut - 0.45f);
    } else if (c > 64) {
      lo = cut; has_lo = true;
      cut = 0.5f * (cut + hi);
    } else {
      // scatter candidates to LDS by rank in (u,lane) order
      int base = 0;
#pragma unroll
      for (int u = 0; u < 32; ++u) {
        bool cd = lg[u] > cut;
        unsigned long long mk = __ballot(cd);
        if (cd) cbuf[w][base + __popcll(mk & below)] = lg[u];
        base += __popcll(mk);
      }
      lds_fence();
      float v = (lane < c) ? cbuf[w][lane] : -FLT_MAX;
      // 64-lane bitonic ascending sort
#pragma unroll
      for (int size = 2; size <= 64; size <<= 1) {
#pragma unroll
        for (int stride = size >> 1; stride; stride >>= 1) {
          float pv = __shfl_xor(v, stride);
          bool lower = (lane & stride) == 0;
          bool asc = (lane & size) == 0;
          v = (lower == asc) ? fminf(v, pv) : fmaxf(v, pv);
        }
      }
      T = __shfl(v, 32);                // 32nd largest
      found = true;
    }
  }
  if (!found) {                          // exact radix bisect fallback
    unsigned tb = 0;
    for (int bit = 31; bit >= 0; --bit) {
      unsigned cand = tb | (1u << bit);
      int c = 0;
#pragma unroll
      for (int u = 0; u < 32; ++u) c += (f2sort(lg[u]) >= cand) ? 1 : 0;
      c = wave_isum(c);
      if (c >= 32) tb = cand;
    }
    T = (tb & 0x80000000u) ? __uint_as_float(tb & 0x7fffffffu) : __uint_as_float(~tb);
  }

  // ---- keep mask: > T, plus ties == T at lowest flat index (lax.top_k semantics)
  int cgt = 0;
#pragma unroll
  for (int u = 0; u < 32; ++u) cgt += (lg[u] > T) ? 1 : 0;
  int need_eq = 32 - wave_isum(cgt);
  unsigned keepm = 0;
  int base_eq = 0;
#pragma unroll
  for (int u = 0; u < 32; ++u) {
    bool gt = lg[u] > T;
    bool eq = lg[u] == T;
    unsigned long long me = __ballot(eq);
    bool kp = gt || (eq && (base_eq + __popcll(me & below)) < need_eq);
    base_eq += __popcll(me);
    keepm |= kp ? (1u << u) : 0u;
  }

  // ---- softmax over kept; others exactly 0 (matches exp(f32min - max) == 0)
  float sum = 0.f;
#pragma unroll
  for (int u = 0; u < 32; ++u) {
    float e = ((keepm >> u) & 1u) ? __expf(lg[u] - m) : 0.f;
    lg[u] = e;
    sum += e;
  }
  sum = wave_fsum(sum);
  float inv = 1.0f / sum;
#pragma unroll
  for (int u = 0; u < 32; ++u) lg[u] *= inv;

#pragma unroll
  for (int u = 0; u < 32; ++u)
    __builtin_nontemporal_store(lg[u], Lrow + u * 64 + lane);

  // ---- gather the 32 kept (prob, index) pairs via LDS rank-scatter
  int base_k = 0;
#pragma unroll
  for (int u = 0; u < 32; ++u) {
    bool kp = (keepm >> u) & 1u;
    unsigned long long mk = __ballot(kp);
    if (kp) {
      int s = base_k + __popcll(mk & below);
      pbuf[w][s] = lg[u];
      ibuf[w][s] = u * 64 + lane;
    }
    base_k += __popcll(mk);
  }
  lds_fence();

  // ---- sparse PV: mixed[d=lane] = sum_i p_i * v_proj[bh][idx_i][lane]
  const float* Vb = Vp + (size_t)bh * L * 64;
  float acc = 0.f;
#pragma unroll
  for (int i = 0; i < 32; ++i) {
    float p = pbuf[w][i];
    int kidx = ibuf[w][i];
    acc = fmaf(p, Vb[(size_t)kidx * 64 + lane], acc);
  }
  const int bb = bh >> 4, hh = bh & 15;
  Mixed[((size_t)(bb * 2048 + q)) * 1024 + hh * 64 + lane] = acc;
}

// ---------------- Output FC: Out[m][n] = sum_k Mixed[m][k] * Wfc[n][k]  (M=4096,N=64,K=1024)
__global__ __launch_bounds__(256) void fc_kernel(const float* __restrict__ Mx,
                                                 const float* __restrict__ Wfc,
                                                 float* __restrict__ Out) {
  __shared__ float As[32][64];
  __shared__ float Ws[64][64];
  const int t = threadIdx.x;
  const int tx = t & 15;
  const int ty = t >> 4;
  const int m0 = blockIdx.x * 32;
  float acc[2][4] = {};
  for (int k0 = 0; k0 < 1024; k0 += 64) {
    __syncthreads();
    {
      int lin = t * 8;
      int rr = lin >> 6, kk = lin & 63;
      *(float4*)&As[rr][kk] = *(const float4*)&Mx[(size_t)(m0 + rr) * 1024 + k0 + kk];
      *(float4*)&As[rr][kk + 4] = *(const float4*)&Mx[(size_t)(m0 + rr) * 1024 + k0 + kk + 4];
    }
    {
      int n = t >> 2;
      int kq = (t & 3) * 16;
#pragma unroll
      for (int u = 0; u < 4; ++u) {
        float4 wv = *(const float4*)&Wfc[(size_t)n * 1024 + k0 + kq + u * 4];
        Ws[kq + u * 4 + 0][n] = wv.x;
        Ws[kq + u * 4 + 1][n] = wv.y;
        Ws[kq + u * 4 + 2][n] = wv.z;
        Ws[kq + u * 4 + 3][n] = wv.w;
      }
    }
    __syncthreads();
#pragma unroll
    for (int kk = 0; kk < 64; ++kk) {
      float a0 = As[ty][kk], a1 = As[ty + 16][kk];
      float4 wv = *(const float4*)&Ws[kk][tx * 4];
      float wr[4] = {wv.x, wv.y, wv.z, wv.w};
#pragma unroll
      for (int j = 0; j < 4; ++j) {
        acc[0][j] = fmaf(a0, wr[j], acc[0][j]);
        acc[1][j] = fmaf(a1, wr[j], acc[1][j]);
      }
    }
  }
#pragma unroll
  for (int i = 0; i < 2; ++i) {
    int mm = m0 + ty + i * 16;
    *(float4*)&Out[(size_t)mm * 64 + tx * 4] =
        make_float4(acc[i][0], acc[i][1], acc[i][2], acc[i][3]);
  }
}

extern "C" void kernel_launch(void* const* d_in, const int* in_sizes, int n_in,
                              void* d_out, int out_size, void* d_ws, size_t ws_size,
                              hipStream_t stream) {
  const float* q    = (const float*)d_in[0];
  const float* k    = (const float*)d_in[1];
  const float* v    = (const float*)d_in[2];
  const float* w_q  = (const float*)d_in[3];
  const float* w_k  = (const float*)d_in[4];
  const float* w_v  = (const float*)d_in[5];
  const float* w_fc = (const float*)d_in[6];

  float* out = (float*)d_out;
  float* probs = out + OUT0;             // probs region doubles as logits scratch

  float* ws = (float*)d_ws;
  float* q_proj = ws;                    // [B][H][L][64], pre-scaled by SCALE
  float* k_proj = ws + 4194304;
  float* v_proj = ws + 2 * 4194304;
  float* mixed  = ws + 3 * 4194304;      // [B*L][1024]

  dim3 blk(256);
  proj_kernel<1024><<<dim3(16, 32), blk, 0, stream>>>(q, w_q, q_proj, SCALE);
  proj_kernel<1024><<<dim3(16, 32), blk, 0, stream>>>(k, w_k, k_proj, 1.0f);
  proj_kernel<64><<<dim3(16, 32), blk, 0, stream>>>(v, w_v, v_proj, 1.0f);
  logits_kernel<<<dim3(32, 16, 32), blk, 0, stream>>>(q_proj, k_proj, probs);
  select_kernel<<<dim3(16384), blk, 0, stream>>>(probs, v_proj, mixed);
  fc_kernel<<<dim3(128), blk, 0, stream>>>(mixed, w_fc, out);
}